// Round 12
// baseline (496.056 us; speedup 1.0000x reference)
//
#include <hip/hip_runtime.h>

typedef __attribute__((ext_vector_type(8))) short short8;
typedef __attribute__((ext_vector_type(4))) short short4v;
typedef __attribute__((ext_vector_type(4))) float float4v;

#define B_ 4
#define H_ 16
#define S_ 2048
#define D_ 128
#define BM 128            // q rows per block: 4 waves x 32 rows (2 reg-blocked sets of 16)
#define NKT64 32          // 64-row K tiles (pass 1)
#define NKT32 64          // 32-row K/V subtiles (pass 2)

#define NSH (B_ * H_ * S_ * D_)                 // shorts per converted tensor
#define NMW ((size_t)B_ * 32 * S_)              // u64 mask words
#define WS_NEED (2ull * (unsigned long long)NSH * 2ull + (unsigned long long)NMW * 8ull)

// fold 1/sqrt(128) and log2(e) into Q: softmax in exp2 domain is identical
#define QSCALE (0.08838834764831845f * 1.4426950408889634f)

// two f32 -> packed bf16x2 (RNE), one instruction
__device__ __forceinline__ unsigned cvtpk(float lo, float hi) {
  unsigned r;
  asm("v_cvt_pk_bf16_f32 %0, %1, %2" : "=v"(r) : "v"(lo), "v"(hi));
  return r;
}

// fp32 -> bf16 bits (fallback kernel only)
__device__ __forceinline__ short f2bf(float f) {
  unsigned u = __float_as_uint(f);
  u = (u + 0x7fffu + ((u >> 16) & 1u)) >> 16;
  return (short)u;
}

// global->LDS direct copy, 16B per lane; lds base wave-uniform, HW writes lane l at base+16*l
__device__ __forceinline__ void gl16(const void* g, void* lds) {
  __builtin_amdgcn_global_load_lds(
      (const __attribute__((address_space(1))) unsigned int*)g,
      (__attribute__((address_space(3))) unsigned int*)lds, 16, 0, 0);
}

// ---------------- pre-pass: K and V^T in MFMA A-fragment order (merged) ----------------
// K layout: [bh][kt64(32)][kf(4)][dc(4)][lane(64)][8], lane = g*16+c
//   element = K[bh][kt64*64 + kf*16 + c][dc*32 + g*8 + e]
// V layout: [bh][kt32(64)][df(8)][lane(64)][8]
//   element = V[bh][kt32*32 + g*8 + e][df*16 + c]
__global__ void prep_kv(const float* __restrict__ Kg, const float* __restrict__ Vg,
                        short* __restrict__ Kf, short* __restrict__ Vf, int half) {
  size_t id = (size_t)blockIdx.x * 256 + threadIdx.x;
  if (blockIdx.x < (unsigned)half) {
    int c  = (int)(id & 15);
    int g  = (int)((id >> 4) & 3);
    int dc = (int)((id >> 6) & 3);
    int kf = (int)((id >> 8) & 3);
    int kt = (int)((id >> 10) & 31);
    size_t bh = id >> 15;
    const float* src = Kg + ((bh * S_ + (size_t)(kt * 64 + kf * 16 + c)) * D_) + dc * 32 + g * 8;
    float4v a = *(const float4v*)src;
    float4v b = *(const float4v*)(src + 4);
    int4 s;
    s.x = (int)cvtpk(a[0], a[1]);
    s.y = (int)cvtpk(a[2], a[3]);
    s.z = (int)cvtpk(b[0], b[1]);
    s.w = (int)cvtpk(b[2], b[3]);
    ((int4*)Kf)[id] = s;
  } else {
    id -= (size_t)half * 256;
    int c   = (int)(id & 15);
    int g   = (int)((id >> 4) & 3);
    int df  = (int)((id >> 6) & 7);
    int kt32= (int)((id >> 9) & 63);
    size_t bh = id >> 15;
    const float* src = Vg + (bh * S_ + (size_t)(kt32 * 32 + g * 8)) * D_ + df * 16 + c;
    float f[8];
#pragma unroll
    for (int e = 0; e < 8; ++e) f[e] = src[(size_t)e * D_];
    int4 s;
    s.x = (int)cvtpk(f[0], f[1]);
    s.y = (int)cvtpk(f[2], f[3]);
    s.z = (int)cvtpk(f[4], f[5]);
    s.w = (int)cvtpk(f[6], f[7]);
    ((int4*)Vf)[id] = s;
  }
}

// ---------------- pre-pass: bit-pack mask via ballot ----------------
// Bits[b][kt64(32)][q(2048)] u64; bit j = (mask[b][q][kt64*64+j] != 0)
__global__ void prep_m(const int* __restrict__ Mg, unsigned long long* __restrict__ Bits) {
  int gw = blockIdx.x * 4 + (threadIdx.x >> 6);   // global wave id, 0..NMW-1
  int j  = threadIdx.x & 63;
  int kt = gw & 31;
  int q  = (gw >> 5) & (S_ - 1);
  int b  = gw >> 16;
  int m = Mg[((size_t)b * S_ + q) * S_ + kt * 64 + j];
  unsigned long long bal = __ballot(m != 0);
  if (j == 0) Bits[((size_t)b * 32 + kt) * S_ + q] = bal;
}

// ---------------- main: fused 2-pass attention, q-register-blocked (2 sets/wave) ----------------
// Each LDS K/V fragment read feeds 2 MFMAs -> LDS-pipe traffic per output halves.
__global__ __launch_bounds__(256, 3) void sdpa_main(
    const float* __restrict__ Qg, const short* __restrict__ Kfr,
    const short* __restrict__ Vfr, const unsigned long long* __restrict__ Bits,
    float* __restrict__ Og, float* __restrict__ Ag) {

  // region A (32KB): pass1 = K dbuf 2x16KB ; pass2 = K dbuf 2x8KB @0 + V dbuf 2x8KB @16384
  // region B (10240B): Ps[128][40] wave-private P transpose (wave w owns rows w*32..w*32+31)
  __shared__ __align__(16) char smem[32768 + 10240];
  short (*Ps)[40] = (short (*)[40])(smem + 32768);

  const int t = threadIdx.x;
  const int w = t >> 6;        // wave 0..3
  const int l = t & 63;
  const int g = l >> 4;

  // XCD swizzle: all 16 q-tiles of one (b,h) land on one XCD (p % 8)
  const int p    = blockIdx.x;
  const int xcd  = p & 7;
  const int slot = p >> 3;               // 0..127 within XCD
  const int grp  = ((slot >> 4) << 3) + xcd;   // 0..63 = b*16+h
  const int qt   = slot & 15;
  const int h    = grp & 15;
  const int b    = grp >> 4;

  const int qbase  = qt * BM;
  const int r0     = w * 32 + (l & 15);  // local row, q-set 0 (set 1 = +16)
  const int qrow0  = qbase + r0;
  const int qrow1  = qrow0 + 16;

  const size_t bhOff = (size_t)(b * H_ + h) * (S_ * D_);
  const short* Kp = Kfr + bhOff;
  const short* Vp = Vfr + bhOff;
  const unsigned long long* Bp = Bits + (size_t)b * 32 * S_;
  const unsigned* Bu = (const unsigned*)Bits;
  float* Op = Og + bhOff;
  float* Ap = Ag + (size_t)(b * H_ + h) * ((size_t)S_ * S_);

  // Q fragments for both q-sets: fp32 load + pack (one-time)
  short8 qf0[4], qf1[4];
#pragma unroll
  for (int dc = 0; dc < 4; ++dc) {
    const float* q0 = Qg + bhOff + (size_t)qrow0 * D_ + dc * 32 + g * 8;
    float4v a = *(const float4v*)q0;
    float4v c4 = *(const float4v*)(q0 + 4);
    int4 s;
    s.x = (int)cvtpk(a[0] * QSCALE, a[1] * QSCALE);
    s.y = (int)cvtpk(a[2] * QSCALE, a[3] * QSCALE);
    s.z = (int)cvtpk(c4[0] * QSCALE, c4[1] * QSCALE);
    s.w = (int)cvtpk(c4[2] * QSCALE, c4[3] * QSCALE);
    qf0[dc] = *(short8*)&s;
    const float* q1 = Qg + bhOff + (size_t)qrow1 * D_ + dc * 32 + g * 8;
    a = *(const float4v*)q1;
    c4 = *(const float4v*)(q1 + 4);
    s.x = (int)cvtpk(a[0] * QSCALE, a[1] * QSCALE);
    s.y = (int)cvtpk(a[2] * QSCALE, a[3] * QSCALE);
    s.z = (int)cvtpk(c4[0] * QSCALE, c4[1] * QSCALE);
    s.w = (int)cvtpk(c4[2] * QSCALE, c4[3] * QSCALE);
    qf1[dc] = *(short8*)&s;
  }

  // =============== pass 1: row sums of exp2(scores), K staged in LDS ===============
  // 16 chunks of 1KB per 64-row tile; wave w stages chunks w*4..w*4+3
#pragma unroll
  for (int i = 0; i < 4; ++i) {
    int f = w * 4 + i;
    gl16(Kp + f * 512 + l * 8, smem + f * 1024);
  }
  __syncthreads();

  float lsA0 = 0.f, lsA1 = 0.f, lsB0 = 0.f, lsB1 = 0.f;
  unsigned long long mbA = Bp[qrow0], mbB = Bp[qrow1];
  int cur = 0;
  for (int kt = 0; kt < NKT64; ++kt) {
    unsigned long long mbA2 = 0, mbB2 = 0;
    if (kt < NKT64 - 1) {   // stage next tile + prefetch next masks
      mbA2 = Bp[(size_t)(kt + 1) * S_ + qrow0];
      mbB2 = Bp[(size_t)(kt + 1) * S_ + qrow1];
      const short* src = Kp + (size_t)(kt + 1) * 8192;
      char* dst = smem + (cur ^ 1) * 16384;
#pragma unroll
      for (int i = 0; i < 4; ++i) {
        int f = w * 4 + i;
        gl16(src + f * 512 + l * 8, dst + f * 1024);
      }
    }
    const char* kb = smem + cur * 16384;

    float4v accA[4], accB[4];
#pragma unroll
    for (int kf = 0; kf < 4; ++kf) { accA[kf] = (float4v){0.f,0.f,0.f,0.f}; accB[kf] = (float4v){0.f,0.f,0.f,0.f}; }
#pragma unroll
    for (int kf = 0; kf < 4; ++kf) {
#pragma unroll
      for (int dc = 0; dc < 4; ++dc) {
        short8 af = *(const short8*)(kb + (kf * 4 + dc) * 1024 + l * 16);  // read once
        accA[kf] = __builtin_amdgcn_mfma_f32_16x16x32_bf16(af, qf0[dc], accA[kf], 0, 0, 0);
        accB[kf] = __builtin_amdgcn_mfma_f32_16x16x32_bf16(af, qf1[dc], accB[kf], 0, 0, 0);
      }
    }
    // lane holds S^T[k = kt*64 + kf*16 + g*4 + r][q] for both q-sets (log2 domain)
#pragma unroll
    for (int kf = 0; kf < 4; ++kf) {
      unsigned mgA = (unsigned)(mbA >> (kf * 16 + g * 4)) & 0xFu;
      float a0 = ((mgA >> 0) & 1) ? __builtin_amdgcn_exp2f(accA[kf][0]) : 0.f;
      float a1 = ((mgA >> 1) & 1) ? __builtin_amdgcn_exp2f(accA[kf][1]) : 0.f;
      float a2 = ((mgA >> 2) & 1) ? __builtin_amdgcn_exp2f(accA[kf][2]) : 0.f;
      float a3 = ((mgA >> 3) & 1) ? __builtin_amdgcn_exp2f(accA[kf][3]) : 0.f;
      if (kf & 1) lsA1 += (a0 + a1) + (a2 + a3); else lsA0 += (a0 + a1) + (a2 + a3);
      unsigned mgB = (unsigned)(mbB >> (kf * 16 + g * 4)) & 0xFu;
      float b0 = ((mgB >> 0) & 1) ? __builtin_amdgcn_exp2f(accB[kf][0]) : 0.f;
      float b1 = ((mgB >> 1) & 1) ? __builtin_amdgcn_exp2f(accB[kf][1]) : 0.f;
      float b2 = ((mgB >> 2) & 1) ? __builtin_amdgcn_exp2f(accB[kf][2]) : 0.f;
      float b3 = ((mgB >> 3) & 1) ? __builtin_amdgcn_exp2f(accB[kf][3]) : 0.f;
      if (kf & 1) lsB1 += (b0 + b1) + (b2 + b3); else lsB0 += (b0 + b1) + (b2 + b3);
    }
    __syncthreads();
    mbA = mbA2; mbB = mbB2;
    cur ^= 1;
  }
  float lsumA = lsA0 + lsA1;
  lsumA += __shfl_xor(lsumA, 16);
  lsumA += __shfl_xor(lsumA, 32);
  const float lgA = (lsumA > 0.f) ? __log2f(lsumA) : 1e30f;
  float lsumB = lsB0 + lsB1;
  lsumB += __shfl_xor(lsumB, 16);
  lsumB += __shfl_xor(lsumB, 32);
  const float lgB = (lsumB > 0.f) ? __log2f(lsumB) : 1e30f;

  // =============== pass 2: attention write + PV, K+V staged in LDS ===============
  // 8 chunks K + 8 chunks V per 32-row subtile; wave w stages chunks {w, w+4} of each
#pragma unroll
  for (int i = 0; i < 2; ++i) {
    int f = w + 4 * i;
    gl16(Kp + f * 512 + l * 8, smem + f * 1024);
    gl16(Vp + f * 512 + l * 8, smem + 16384 + f * 1024);
  }
  __syncthreads();

  float4v accoA[8], accoB[8];
#pragma unroll
  for (int df = 0; df < 8; ++df) { accoA[df] = (float4v){0.f,0.f,0.f,0.f}; accoB[df] = (float4v){0.f,0.f,0.f,0.f}; }

  unsigned mwA = Bu[((size_t)(b * 32) * S_ + qrow0) * 2];
  unsigned mwB = Bu[((size_t)(b * 32) * S_ + qrow1) * 2];
  cur = 0;
  for (int kt = 0; kt < NKT32; ++kt) {
    unsigned mwA2 = 0, mwB2 = 0;
    if (kt < NKT32 - 1) {
      mwA2 = Bu[((size_t)(b * 32 + ((kt + 1) >> 1)) * S_ + qrow0) * 2 + ((kt + 1) & 1)];
      mwB2 = Bu[((size_t)(b * 32 + ((kt + 1) >> 1)) * S_ + qrow1) * 2 + ((kt + 1) & 1)];
      const short* ks = Kp + (size_t)(kt + 1) * 4096;
      const short* vs = Vp + (size_t)(kt + 1) * 4096;
      char* kd = smem + (cur ^ 1) * 8192;
      char* vd = smem + 16384 + (cur ^ 1) * 8192;
#pragma unroll
      for (int i = 0; i < 2; ++i) {
        int f = w + 4 * i;
        gl16(ks + f * 512 + l * 8, kd + f * 1024);
        gl16(vs + f * 512 + l * 8, vd + f * 1024);
      }
    }
    const char* kb = smem + cur * 8192;
    const char* vb = smem + 16384 + cur * 8192;

    float4v accA[2], accB[2];
#pragma unroll
    for (int kf = 0; kf < 2; ++kf) { accA[kf] = (float4v){0.f,0.f,0.f,0.f}; accB[kf] = (float4v){0.f,0.f,0.f,0.f}; }
#pragma unroll
    for (int kf = 0; kf < 2; ++kf) {
#pragma unroll
      for (int dc = 0; dc < 4; ++dc) {
        short8 af = *(const short8*)(kb + (kf * 4 + dc) * 1024 + l * 16);  // read once
        accA[kf] = __builtin_amdgcn_mfma_f32_16x16x32_bf16(af, qf0[dc], accA[kf], 0, 0, 0);
        accB[kf] = __builtin_amdgcn_mfma_f32_16x16x32_bf16(af, qf1[dc], accB[kf], 0, 0, 0);
      }
    }

    // normalized probabilities: pn = exp2(score - log2(rowsum)); bf16 into Ps
    float4v awA[2], awB[2];
#pragma unroll
    for (int kf = 0; kf < 2; ++kf) {
      unsigned mgA = (mwA >> (kf * 16 + g * 4)) & 0xFu;
#pragma unroll
      for (int r = 0; r < 4; ++r) {
        float arg = ((mgA >> r) & 1) ? (accA[kf][r] - lgA) : -1e30f;
        awA[kf][r] = __builtin_amdgcn_exp2f(arg);
      }
      int2 pb;
      pb.x = (int)cvtpk(awA[kf][0], awA[kf][1]);
      pb.y = (int)cvtpk(awA[kf][2], awA[kf][3]);
      *(int2*)&Ps[r0][kf * 16 + g * 4] = pb;
      unsigned mgB = (mwB >> (kf * 16 + g * 4)) & 0xFu;
#pragma unroll
      for (int r = 0; r < 4; ++r) {
        float arg = ((mgB >> r) & 1) ? (accB[kf][r] - lgB) : -1e30f;
        awB[kf][r] = __builtin_amdgcn_exp2f(arg);
      }
      pb.x = (int)cvtpk(awB[kf][0], awB[kf][1]);
      pb.y = (int)cvtpk(awB[kf][2], awB[kf][3]);
      *(int2*)&Ps[r0 + 16][kf * 16 + g * 4] = pb;
    }

    // PV on the critical path: V fragment read once, feeds both q-sets
    {
      short8 pbfA = *(const short8*)&Ps[r0][g * 8];
      short8 pbfB = *(const short8*)&Ps[r0 + 16][g * 8];
#pragma unroll
      for (int df = 0; df < 8; ++df) {
        short8 vf = *(const short8*)(vb + df * 1024 + l * 16);
        accoA[df] = __builtin_amdgcn_mfma_f32_16x16x32_bf16(vf, pbfA, accoA[df], 0, 0, 0);
        accoB[df] = __builtin_amdgcn_mfma_f32_16x16x32_bf16(vf, pbfB, accoB[df], 0, 0, 0);
      }
    }
    // attention stores (feed nothing)
#pragma unroll
    for (int kf = 0; kf < 2; ++kf) {
      int k0 = kt * 32 + kf * 16 + g * 4;
      __builtin_nontemporal_store(awA[kf], (float4v*)(Ap + (size_t)qrow0 * S_ + k0));
      __builtin_nontemporal_store(awB[kf], (float4v*)(Ap + (size_t)qrow1 * S_ + k0));
    }
    __syncthreads();
    mwA = mwA2; mwB = mwB2;
    cur ^= 1;
  }

#pragma unroll
  for (int df = 0; df < 8; ++df) {
    __builtin_nontemporal_store(accoA[df], (float4v*)(Op + (size_t)qrow0 * D_ + df * 16 + g * 4));
    __builtin_nontemporal_store(accoB[df], (float4v*)(Op + (size_t)qrow1 * D_ + df * 16 + g * 4));
  }
}

// ================= fallback (round-1 kernel) if ws too small =================
#define LQK 136
#define LVT 72

__global__ __launch_bounds__(256, 3) void sdpa_fallback(
    const float* __restrict__ Qg, const float* __restrict__ Kg,
    const float* __restrict__ Vg, const int* __restrict__ Mg,
    float* __restrict__ Og, float* __restrict__ Ag) {

  __shared__ __align__(16) char smemf[17408 + 27648];
  short (*Ks)[LQK]  = (short (*)[LQK])(smemf);
  short (*Qs)[LQK]  = (short (*)[LQK])(smemf + 17408);
  short (*VTs)[LVT] = (short (*)[LVT])(smemf + 17408);
  short (*Psf)[LVT] = (short (*)[LVT])(smemf + 17408 + 18432);

  const int t = threadIdx.x;
  const int w = t >> 6;
  const int l = t & 63;
  const int g = l >> 4;
  const int c = l & 15;

  const int bid = blockIdx.x;
  const int qt = bid & 31;
  const int h  = (bid >> 5) & 15;
  const int b  = bid >> 9;

  const int qbase  = qt * 64;
  const int qrow_l = w * 16 + c;
  const int qrow   = qbase + qrow_l;

  const size_t bhOff = (size_t)(b * H_ + h) * (S_ * D_);
  const float* Qp = Qg + bhOff;
  const float* Kp = Kg + bhOff;
  const float* Vp = Vg + bhOff;
  const int*   Mp = Mg + (size_t)b * S_ * S_;
  float* Op = Og + bhOff;
  float* Ap = Ag + (size_t)(b * H_ + h) * ((size_t)S_ * S_);

#pragma unroll
  for (int i = 0; i < 8; ++i) {
    int idx = t + i * 256;
    int d4 = idx & 31, row = idx >> 5;
    float4v v = *(const float4v*)(Qp + (size_t)(qbase + row) * D_ + d4 * 4);
    short4v s;
    s[0] = f2bf(v[0] * QSCALE); s[1] = f2bf(v[1] * QSCALE);
    s[2] = f2bf(v[2] * QSCALE); s[3] = f2bf(v[3] * QSCALE);
    *(short4v*)&Qs[row][d4 * 4] = s;
  }
  __syncthreads();

  short8 qf[4];
#pragma unroll
  for (int dc = 0; dc < 4; ++dc)
    qf[dc] = *(const short8*)&Qs[qrow_l][dc * 32 + g * 8];

  float m_run = -1e30f, l_run = 0.f;
  for (int kt = 0; kt < 32; ++kt) {
    __syncthreads();
#pragma unroll
    for (int i = 0; i < 8; ++i) {
      int idx = t + i * 256;
      int d4 = idx & 31, row = idx >> 5;
      float4v v = *(const float4v*)(Kp + (size_t)(kt * 64 + row) * D_ + d4 * 4);
      short4v s;
      s[0] = f2bf(v[0]); s[1] = f2bf(v[1]); s[2] = f2bf(v[2]); s[3] = f2bf(v[3]);
      *(short4v*)&Ks[row][d4 * 4] = s;
    }
    __syncthreads();

    float4v acc[4];
#pragma unroll
    for (int kf = 0; kf < 4; ++kf) acc[kf] = (float4v){0.f, 0.f, 0.f, 0.f};
#pragma unroll
    for (int kf = 0; kf < 4; ++kf) {
#pragma unroll
      for (int dc = 0; dc < 4; ++dc) {
        short8 af = *(const short8*)&Ks[kf * 16 + c][dc * 32 + g * 8];
        acc[kf] = __builtin_amdgcn_mfma_f32_16x16x32_bf16(af, qf[dc], acc[kf], 0, 0, 0);
      }
    }

    float sv[4][4];
    float tmax = -1e30f;
#pragma unroll
    for (int kf = 0; kf < 4; ++kf) {
      int k0 = kt * 64 + kf * 16 + g * 4;
      const int4 mv = *(const int4*)(Mp + (size_t)qrow * S_ + k0);
      int mr[4] = {mv.x, mv.y, mv.z, mv.w};
#pragma unroll
      for (int r = 0; r < 4; ++r) {
        float x = acc[kf][r];
        x = (mr[r] == 0) ? -1e9f : x;
        sv[kf][r] = x;
        tmax = fmaxf(tmax, x);
      }
    }
    tmax = fmaxf(tmax, __shfl_xor(tmax, 16));
    tmax = fmaxf(tmax, __shfl_xor(tmax, 32));
    float newm = fmaxf(m_run, tmax);
    float tsum = 0.f;
#pragma unroll
    for (int kf = 0; kf < 4; ++kf)
#pragma unroll
      for (int r = 0; r < 4; ++r)
        tsum += __builtin_amdgcn_exp2f(sv[kf][r] - newm);
    tsum += __shfl_xor(tsum, 16);
    tsum += __shfl_xor(tsum, 32);
    l_run = l_run * __builtin_amdgcn_exp2f(m_run - newm) + tsum;
    m_run = newm;
  }

  const float rl = 1.0f / l_run;

  float4v acco[8];
#pragma unroll
  for (int df = 0; df < 8; ++df) acco[df] = (float4v){0.f, 0.f, 0.f, 0.f};

  for (int kt = 0; kt < 32; ++kt) {
    __syncthreads();
#pragma unroll
    for (int i = 0; i < 8; ++i) {
      int idx = t + i * 256;
      int d4 = idx & 31, row = idx >> 5;
      float4v v = *(const float4v*)(Kp + (size_t)(kt * 64 + row) * D_ + d4 * 4);
      short4v s;
      s[0] = f2bf(v[0]); s[1] = f2bf(v[1]); s[2] = f2bf(v[2]); s[3] = f2bf(v[3]);
      *(short4v*)&Ks[row][d4 * 4] = s;
    }
#pragma unroll
    for (int i = 0; i < 8; ++i) {
      int idx = t + i * 256;
      int d = idx & 127, kq = idx >> 7;
      const float* vp = Vp + (size_t)(kt * 64 + kq * 4) * D_ + d;
      short4v s;
      s[0] = f2bf(vp[0]); s[1] = f2bf(vp[D_]); s[2] = f2bf(vp[2 * D_]); s[3] = f2bf(vp[3 * D_]);
      *(short4v*)&VTs[d][kq * 4] = s;
    }
    __syncthreads();

    float4v acc[4];
#pragma unroll
    for (int kf = 0; kf < 4; ++kf) acc[kf] = (float4v){0.f, 0.f, 0.f, 0.f};
#pragma unroll
    for (int kf = 0; kf < 4; ++kf) {
#pragma unroll
      for (int dc = 0; dc < 4; ++dc) {
        short8 af = *(const short8*)&Ks[kf * 16 + c][dc * 32 + g * 8];
        acc[kf] = __builtin_amdgcn_mfma_f32_16x16x32_bf16(af, qf[dc], acc[kf], 0, 0, 0);
      }
    }

#pragma unroll
    for (int kf = 0; kf < 4; ++kf) {
      int k0 = kt * 64 + kf * 16 + g * 4;
      const int4 mv = *(const int4*)(Mp + (size_t)qrow * S_ + k0);
      int mr[4] = {mv.x, mv.y, mv.z, mv.w};
      float4v aw;
      short4v pb;
#pragma unroll
      for (int r = 0; r < 4; ++r) {
        float x = acc[kf][r];
        x = (mr[r] == 0) ? -1e9f : x;
        float pn = __builtin_amdgcn_exp2f(x - m_run) * rl;
        aw[r] = pn;
        pb[r] = f2bf(pn);
      }
      __builtin_nontemporal_store(aw, (float4v*)(Ap + (size_t)qrow * S_ + k0));
      *(short4v*)&Psf[qrow_l][kf * 16 + g * 4] = pb;
    }

#pragma unroll
    for (int kc = 0; kc < 2; ++kc) {
      short8 pbf = *(const short8*)&Psf[qrow_l][kc * 32 + g * 8];
#pragma unroll
      for (int df = 0; df < 8; ++df) {
        short8 vf = *(const short8*)&VTs[df * 16 + c][kc * 32 + g * 8];
        acco[df] = __builtin_amdgcn_mfma_f32_16x16x32_bf16(vf, pbf, acco[df], 0, 0, 0);
      }
    }
  }

#pragma unroll
  for (int df = 0; df < 8; ++df) {
    *(float4v*)(Op + (size_t)qrow * D_ + df * 16 + g * 4) = acco[df];
  }
}

extern "C" void kernel_launch(void* const* d_in, const int* in_sizes, int n_in,
                              void* d_out, int out_size, void* d_ws, size_t ws_size,
                              hipStream_t stream) {
  const float* Q = (const float*)d_in[0];
  const float* K = (const float*)d_in[1];
  const float* V = (const float*)d_in[2];
  const int*   M = (const int*)d_in[3];
  float* Out  = (float*)d_out;
  float* Attn = Out + (size_t)B_ * H_ * S_ * D_;

  if (ws_size >= WS_NEED) {
    short* Kf = (short*)d_ws;
    short* Vf = Kf + (size_t)NSH;
    unsigned long long* Bits = (unsigned long long*)(Vf + (size_t)NSH);
    const int pgrid = NSH / 8 / 256;  // 8192
    prep_kv<<<dim3(pgrid * 2), dim3(256), 0, stream>>>(K, V, Kf, Vf, pgrid);
    prep_m<<<dim3((unsigned)(NMW / 4)), dim3(256), 0, stream>>>(M, Bits);
    sdpa_main<<<dim3(B_ * H_ * (S_ / BM)), dim3(256), 0, stream>>>(
        Q, Kf, Vf, Bits, Out, Attn);
  } else {
    sdpa_fallback<<<dim3(B_ * H_ * 32), dim3(256), 0, stream>>>(Q, K, V, M, Out, Attn);
  }
}

// Round 13
// 430.565 us; speedup vs baseline: 1.1521x; 1.1521x over previous
//
#include <hip/hip_runtime.h>

typedef __attribute__((ext_vector_type(8))) short short8;
typedef __attribute__((ext_vector_type(4))) short short4v;
typedef __attribute__((ext_vector_type(4))) float float4v;

#define B_ 4
#define H_ 16
#define S_ 2048
#define D_ 128
#define BM 64
#define NKT64 32          // 64-row K tiles (pass 1)
#define NKT32 64          // 32-row K/V subtiles (pass 2)

#define NSH (B_ * H_ * S_ * D_)                 // shorts per converted tensor
#define NMW ((size_t)B_ * 32 * S_)              // u64 mask words
#define WS_NEED (2ull * (unsigned long long)NSH * 2ull + (unsigned long long)NMW * 8ull)

// fold 1/sqrt(128) and log2(e) into Q: softmax in exp2 domain is identical
#define QSCALE (0.08838834764831845f * 1.4426950408889634f)

// two f32 -> packed bf16x2 (RNE), one instruction
__device__ __forceinline__ unsigned cvtpk(float lo, float hi) {
  unsigned r;
  asm("v_cvt_pk_bf16_f32 %0, %1, %2" : "=v"(r) : "v"(lo), "v"(hi));
  return r;
}

// fp32 -> bf16 bits (fallback kernel only)
__device__ __forceinline__ short f2bf(float f) {
  unsigned u = __float_as_uint(f);
  u = (u + 0x7fffu + ((u >> 16) & 1u)) >> 16;
  return (short)u;
}

// global->LDS direct copy, 16B per lane; lds base wave-uniform, HW writes lane l at base+16*l
__device__ __forceinline__ void gl16(const void* g, void* lds) {
  __builtin_amdgcn_global_load_lds(
      (const __attribute__((address_space(1))) unsigned int*)g,
      (__attribute__((address_space(3))) unsigned int*)lds, 16, 0, 0);
}

// ---------------- pre-pass: K and V^T in MFMA A-fragment order (merged) ----------------
// K layout: [bh][kt64(32)][kf(4)][dc(4)][lane(64)][8], lane = g*16+c
//   element = K[bh][kt64*64 + kf*16 + c][dc*32 + g*8 + e]
// V layout: [bh][kt32(64)][df(8)][lane(64)][8]
//   element = V[bh][kt32*32 + g*8 + e][df*16 + c]
__global__ void prep_kv(const float* __restrict__ Kg, const float* __restrict__ Vg,
                        short* __restrict__ Kf, short* __restrict__ Vf, int half) {
  size_t id = (size_t)blockIdx.x * 256 + threadIdx.x;
  if (blockIdx.x < (unsigned)half) {
    int c  = (int)(id & 15);
    int g  = (int)((id >> 4) & 3);
    int dc = (int)((id >> 6) & 3);
    int kf = (int)((id >> 8) & 3);
    int kt = (int)((id >> 10) & 31);
    size_t bh = id >> 15;
    const float* src = Kg + ((bh * S_ + (size_t)(kt * 64 + kf * 16 + c)) * D_) + dc * 32 + g * 8;
    float4v a = *(const float4v*)src;
    float4v b = *(const float4v*)(src + 4);
    int4 s;
    s.x = (int)cvtpk(a[0], a[1]);
    s.y = (int)cvtpk(a[2], a[3]);
    s.z = (int)cvtpk(b[0], b[1]);
    s.w = (int)cvtpk(b[2], b[3]);
    ((int4*)Kf)[id] = s;
  } else {
    id -= (size_t)half * 256;
    int c   = (int)(id & 15);
    int g   = (int)((id >> 4) & 3);
    int df  = (int)((id >> 6) & 7);
    int kt32= (int)((id >> 9) & 63);
    size_t bh = id >> 15;
    const float* src = Vg + (bh * S_ + (size_t)(kt32 * 32 + g * 8)) * D_ + df * 16 + c;
    float f[8];
#pragma unroll
    for (int e = 0; e < 8; ++e) f[e] = src[(size_t)e * D_];
    int4 s;
    s.x = (int)cvtpk(f[0], f[1]);
    s.y = (int)cvtpk(f[2], f[3]);
    s.z = (int)cvtpk(f[4], f[5]);
    s.w = (int)cvtpk(f[6], f[7]);
    ((int4*)Vf)[id] = s;
  }
}

// ---------------- pre-pass: bit-pack mask via ballot ----------------
// Bits[b][kt64(32)][q(2048)] u64; bit j = (mask[b][q][kt64*64+j] != 0)
__global__ void prep_m(const int* __restrict__ Mg, unsigned long long* __restrict__ Bits) {
  int gw = blockIdx.x * 4 + (threadIdx.x >> 6);   // global wave id, 0..NMW-1
  int j  = threadIdx.x & 63;
  int kt = gw & 31;
  int q  = (gw >> 5) & (S_ - 1);
  int b  = gw >> 16;
  int m = Mg[((size_t)b * S_ + q) * S_ + kt * 64 + j];
  unsigned long long bal = __ballot(m != 0);
  if (j == 0) Bits[((size_t)b * 32 + kt) * S_ + q] = bal;
}

// ---------------- main: fused 2-pass attention, LDS dbuf, XCD-swizzled ----------------
__global__ __launch_bounds__(256, 4) void sdpa_main(
    const float* __restrict__ Qg, const short* __restrict__ Kfr,
    const short* __restrict__ Vfr, const unsigned long long* __restrict__ Bits,
    float* __restrict__ Og, float* __restrict__ Ag) {

  // region A (32KB): pass1 = K dbuf 2x16KB ; pass2 = K dbuf 2x8KB @0 + V dbuf 2x8KB @16384
  // region B (5120B): Ps[64][40] wave-private P transpose
  __shared__ __align__(16) char smem[32768 + 5120];
  short (*Ps)[40] = (short (*)[40])(smem + 32768);

  const int t = threadIdx.x;
  const int w = t >> 6;
  const int l = t & 63;
  const int g = l >> 4;

  // XCD swizzle: all 32 q-tiles of one (b,h) land on one XCD (p % 8)
  const int p    = blockIdx.x;
  const int xcd  = p & 7;
  const int slot = p >> 3;               // 0..255 within XCD
  const int grp  = ((slot >> 5) << 3) + xcd;   // 0..63 = b*16+h
  const int qt   = slot & 31;
  const int h    = grp & 15;
  const int b    = grp >> 4;

  const int qbase  = qt * BM;
  const int qrow_l = w * 16 + (l & 15);
  const int qrow   = qbase + qrow_l;

  const size_t bhOff = (size_t)(b * H_ + h) * (S_ * D_);
  const short* Kp = Kfr + bhOff;
  const short* Vp = Vfr + bhOff;
  const unsigned long long* Bp = Bits + (size_t)b * 32 * S_;
  const unsigned* Bu = (const unsigned*)Bits;
  float* Op = Og + bhOff;
  float* Ap = Ag + (size_t)(b * H_ + h) * ((size_t)S_ * S_);

  // Q fragments: fp32 load + pack (one-time)
  short8 qf[4];
#pragma unroll
  for (int dc = 0; dc < 4; ++dc) {
    const float* qsrc = Qg + bhOff + (size_t)qrow * D_ + dc * 32 + g * 8;
    float4v a = *(const float4v*)qsrc;
    float4v c4 = *(const float4v*)(qsrc + 4);
    int4 s;
    s.x = (int)cvtpk(a[0] * QSCALE, a[1] * QSCALE);
    s.y = (int)cvtpk(a[2] * QSCALE, a[3] * QSCALE);
    s.z = (int)cvtpk(c4[0] * QSCALE, c4[1] * QSCALE);
    s.w = (int)cvtpk(c4[2] * QSCALE, c4[3] * QSCALE);
    qf[dc] = *(short8*)&s;
  }

  // =============== pass 1: row sums of exp2(scores), K staged in LDS ===============
#pragma unroll
  for (int i = 0; i < 4; ++i) {
    int f = w * 4 + i;
    gl16(Kp + f * 512 + l * 8, smem + f * 1024);
  }
  __syncthreads();

  float ls0 = 0.f, ls1 = 0.f, ls2 = 0.f, ls3 = 0.f;
  unsigned long long mb = Bp[qrow];       // tile-0 mask
  int cur = 0;
  for (int kt = 0; kt < NKT64; ++kt) {
    unsigned long long mb_next = 0;
    if (kt < NKT64 - 1) {   // stage next tile + prefetch next mask
      mb_next = Bp[(size_t)(kt + 1) * S_ + qrow];
      const short* src = Kp + (size_t)(kt + 1) * 8192;
      char* dst = smem + (cur ^ 1) * 16384;
#pragma unroll
      for (int i = 0; i < 4; ++i) {
        int f = w * 4 + i;
        gl16(src + f * 512 + l * 8, dst + f * 1024);
      }
    }
    const char* kb = smem + cur * 16384;

    float4v acc[4];
#pragma unroll
    for (int kf = 0; kf < 4; ++kf) acc[kf] = (float4v){0.f, 0.f, 0.f, 0.f};
#pragma unroll
    for (int kf = 0; kf < 4; ++kf) {
#pragma unroll
      for (int dc = 0; dc < 4; ++dc) {
        short8 af = *(const short8*)(kb + (kf * 4 + dc) * 1024 + l * 16);
        acc[kf] = __builtin_amdgcn_mfma_f32_16x16x32_bf16(af, qf[dc], acc[kf], 0, 0, 0);
      }
    }
    // lane holds S^T[k = kt*64 + kf*16 + g*4 + r][q = l&15] (log2 domain)
#pragma unroll
    for (int kf = 0; kf < 4; ++kf) {
      unsigned mg = (unsigned)(mb >> (kf * 16 + g * 4)) & 0xFu;
      float p0 = ((mg >> 0) & 1) ? __builtin_amdgcn_exp2f(acc[kf][0]) : 0.f;
      float p1 = ((mg >> 1) & 1) ? __builtin_amdgcn_exp2f(acc[kf][1]) : 0.f;
      float p2 = ((mg >> 2) & 1) ? __builtin_amdgcn_exp2f(acc[kf][2]) : 0.f;
      float p3 = ((mg >> 3) & 1) ? __builtin_amdgcn_exp2f(acc[kf][3]) : 0.f;
      if (kf == 0) ls0 += (p0 + p1) + (p2 + p3);
      else if (kf == 1) ls1 += (p0 + p1) + (p2 + p3);
      else if (kf == 2) ls2 += (p0 + p1) + (p2 + p3);
      else ls3 += (p0 + p1) + (p2 + p3);
    }
    __syncthreads();
    mb = mb_next;
    cur ^= 1;
  }
  float lsum = (ls0 + ls1) + (ls2 + ls3);
  lsum += __shfl_xor(lsum, 16);
  lsum += __shfl_xor(lsum, 32);
  const float lg = (lsum > 0.f) ? __log2f(lsum) : 1e30f;

  // =============== pass 2: attention write + PV, K+V staged in LDS ===============
#pragma unroll
  for (int i = 0; i < 2; ++i) {
    int f = w + 4 * i;
    gl16(Kp + f * 512 + l * 8, smem + f * 1024);
    gl16(Vp + f * 512 + l * 8, smem + 16384 + f * 1024);
  }
  __syncthreads();

  float4v acco[8];
#pragma unroll
  for (int df = 0; df < 8; ++df) acco[df] = (float4v){0.f, 0.f, 0.f, 0.f};

  unsigned mw = Bu[((size_t)(b * 32) * S_ + qrow) * 2];
  cur = 0;
  for (int kt = 0; kt < NKT32; ++kt) {
    unsigned mw_next = 0;
    if (kt < NKT32 - 1) {
      mw_next = Bu[((size_t)(b * 32 + ((kt + 1) >> 1)) * S_ + qrow) * 2 + ((kt + 1) & 1)];
      const short* ks = Kp + (size_t)(kt + 1) * 4096;
      const short* vs = Vp + (size_t)(kt + 1) * 4096;
      char* kd = smem + (cur ^ 1) * 8192;
      char* vd = smem + 16384 + (cur ^ 1) * 8192;
#pragma unroll
      for (int i = 0; i < 2; ++i) {
        int f = w + 4 * i;
        gl16(ks + f * 512 + l * 8, kd + f * 1024);
        gl16(vs + f * 512 + l * 8, vd + f * 1024);
      }
    }
    const char* kb = smem + cur * 8192;
    const char* vb = smem + 16384 + cur * 8192;

    float4v acc[2];
#pragma unroll
    for (int kf = 0; kf < 2; ++kf) acc[kf] = (float4v){0.f, 0.f, 0.f, 0.f};
#pragma unroll
    for (int kf = 0; kf < 2; ++kf) {
#pragma unroll
      for (int dc = 0; dc < 4; ++dc) {
        short8 af = *(const short8*)(kb + (kf * 4 + dc) * 1024 + l * 16);
        acc[kf] = __builtin_amdgcn_mfma_f32_16x16x32_bf16(af, qf[dc], acc[kf], 0, 0, 0);
      }
    }

    // normalized probabilities: pn = exp2(score - log2(rowsum)); bf16 into Ps first
    float4v aw[2];
#pragma unroll
    for (int kf = 0; kf < 2; ++kf) {
      unsigned mg = (mw >> (kf * 16 + g * 4)) & 0xFu;
#pragma unroll
      for (int r = 0; r < 4; ++r) {
        float arg = ((mg >> r) & 1) ? (acc[kf][r] - lg) : -1e30f;
        aw[kf][r] = __builtin_amdgcn_exp2f(arg);
      }
      int2 pb;
      pb.x = (int)cvtpk(aw[kf][0], aw[kf][1]);
      pb.y = (int)cvtpk(aw[kf][2], aw[kf][3]);
      *(int2*)&Ps[qrow_l][kf * 16 + g * 4] = pb;
    }

    // PV first (critical path), then the attention stores (feed nothing)
    {
      short8 pbf = *(const short8*)&Ps[qrow_l][g * 8];
#pragma unroll
      for (int df = 0; df < 8; ++df) {
        short8 vf = *(const short8*)(vb + df * 1024 + l * 16);
        acco[df] = __builtin_amdgcn_mfma_f32_16x16x32_bf16(vf, pbf, acco[df], 0, 0, 0);
      }
    }
#pragma unroll
    for (int kf = 0; kf < 2; ++kf) {
      int k0 = kt * 32 + kf * 16 + g * 4;
      __builtin_nontemporal_store(aw[kf], (float4v*)(Ap + (size_t)qrow * S_ + k0));
    }
    __syncthreads();
    mw = mw_next;
    cur ^= 1;
  }

#pragma unroll
  for (int df = 0; df < 8; ++df) {
    __builtin_nontemporal_store(acco[df], (float4v*)(Op + (size_t)qrow * D_ + df * 16 + g * 4));
  }
}

// ================= fallback (round-1 kernel) if ws too small =================
#define LQK 136
#define LVT 72

__global__ __launch_bounds__(256, 3) void sdpa_fallback(
    const float* __restrict__ Qg, const float* __restrict__ Kg,
    const float* __restrict__ Vg, const int* __restrict__ Mg,
    float* __restrict__ Og, float* __restrict__ Ag) {

  __shared__ __align__(16) char smemf[17408 + 27648];
  short (*Ks)[LQK]  = (short (*)[LQK])(smemf);
  short (*Qs)[LQK]  = (short (*)[LQK])(smemf + 17408);
  short (*VTs)[LVT] = (short (*)[LVT])(smemf + 17408);
  short (*Psf)[LVT] = (short (*)[LVT])(smemf + 17408 + 18432);

  const int t = threadIdx.x;
  const int w = t >> 6;
  const int l = t & 63;
  const int g = l >> 4;
  const int c = l & 15;

  const int bid = blockIdx.x;
  const int qt = bid & 31;
  const int h  = (bid >> 5) & 15;
  const int b  = bid >> 9;

  const int qbase  = qt * 64;
  const int qrow_l = w * 16 + c;
  const int qrow   = qbase + qrow_l;

  const size_t bhOff = (size_t)(b * H_ + h) * (S_ * D_);
  const float* Qp = Qg + bhOff;
  const float* Kp = Kg + bhOff;
  const float* Vp = Vg + bhOff;
  const int*   Mp = Mg + (size_t)b * S_ * S_;
  float* Op = Og + bhOff;
  float* Ap = Ag + (size_t)(b * H_ + h) * ((size_t)S_ * S_);

#pragma unroll
  for (int i = 0; i < 8; ++i) {
    int idx = t + i * 256;
    int d4 = idx & 31, row = idx >> 5;
    float4v v = *(const float4v*)(Qp + (size_t)(qbase + row) * D_ + d4 * 4);
    short4v s;
    s[0] = f2bf(v[0] * QSCALE); s[1] = f2bf(v[1] * QSCALE);
    s[2] = f2bf(v[2] * QSCALE); s[3] = f2bf(v[3] * QSCALE);
    *(short4v*)&Qs[row][d4 * 4] = s;
  }
  __syncthreads();

  short8 qf[4];
#pragma unroll
  for (int dc = 0; dc < 4; ++dc)
    qf[dc] = *(const short8*)&Qs[qrow_l][dc * 32 + g * 8];

  float m_run = -1e30f, l_run = 0.f;
  for (int kt = 0; kt < 32; ++kt) {
    __syncthreads();
#pragma unroll
    for (int i = 0; i < 8; ++i) {
      int idx = t + i * 256;
      int d4 = idx & 31, row = idx >> 5;
      float4v v = *(const float4v*)(Kp + (size_t)(kt * 64 + row) * D_ + d4 * 4);
      short4v s;
      s[0] = f2bf(v[0]); s[1] = f2bf(v[1]); s[2] = f2bf(v[2]); s[3] = f2bf(v[3]);
      *(short4v*)&Ks[row][d4 * 4] = s;
    }
    __syncthreads();

    float4v acc[4];
#pragma unroll
    for (int kf = 0; kf < 4; ++kf) acc[kf] = (float4v){0.f, 0.f, 0.f, 0.f};
#pragma unroll
    for (int kf = 0; kf < 4; ++kf) {
#pragma unroll
      for (int dc = 0; dc < 4; ++dc) {
        short8 af = *(const short8*)&Ks[kf * 16 + c][dc * 32 + g * 8];
        acc[kf] = __builtin_amdgcn_mfma_f32_16x16x32_bf16(af, qf[dc], acc[kf], 0, 0, 0);
      }
    }

    float sv[4][4];
    float tmax = -1e30f;
#pragma unroll
    for (int kf = 0; kf < 4; ++kf) {
      int k0 = kt * 64 + kf * 16 + g * 4;
      const int4 mv = *(const int4*)(Mp + (size_t)qrow * S_ + k0);
      int mr[4] = {mv.x, mv.y, mv.z, mv.w};
#pragma unroll
      for (int r = 0; r < 4; ++r) {
        float x = acc[kf][r];
        x = (mr[r] == 0) ? -1e9f : x;
        sv[kf][r] = x;
        tmax = fmaxf(tmax, x);
      }
    }
    tmax = fmaxf(tmax, __shfl_xor(tmax, 16));
    tmax = fmaxf(tmax, __shfl_xor(tmax, 32));
    float newm = fmaxf(m_run, tmax);
    float tsum = 0.f;
#pragma unroll
    for (int kf = 0; kf < 4; ++kf)
#pragma unroll
      for (int r = 0; r < 4; ++r)
        tsum += __builtin_amdgcn_exp2f(sv[kf][r] - newm);
    tsum += __shfl_xor(tsum, 16);
    tsum += __shfl_xor(tsum, 32);
    l_run = l_run * __builtin_amdgcn_exp2f(m_run - newm) + tsum;
    m_run = newm;
  }

  const float rl = 1.0f / l_run;

  float4v acco[8];
#pragma unroll
  for (int df = 0; df < 8; ++df) acco[df] = (float4v){0.f, 0.f, 0.f, 0.f};

  for (int kt = 0; kt < 32; ++kt) {
    __syncthreads();
#pragma unroll
    for (int i = 0; i < 8; ++i) {
      int idx = t + i * 256;
      int d4 = idx & 31, row = idx >> 5;
      float4v v = *(const float4v*)(Kp + (size_t)(kt * 64 + row) * D_ + d4 * 4);
      short4v s;
      s[0] = f2bf(v[0]); s[1] = f2bf(v[1]); s[2] = f2bf(v[2]); s[3] = f2bf(v[3]);
      *(short4v*)&Ks[row][d4 * 4] = s;
    }
#pragma unroll
    for (int i = 0; i < 8; ++i) {
      int idx = t + i * 256;
      int d = idx & 127, kq = idx >> 7;
      const float* vp = Vp + (size_t)(kt * 64 + kq * 4) * D_ + d;
      short4v s;
      s[0] = f2bf(vp[0]); s[1] = f2bf(vp[D_]); s[2] = f2bf(vp[2 * D_]); s[3] = f2bf(vp[3 * D_]);
      *(short4v*)&VTs[d][kq * 4] = s;
    }
    __syncthreads();

    float4v acc[4];
#pragma unroll
    for (int kf = 0; kf < 4; ++kf) acc[kf] = (float4v){0.f, 0.f, 0.f, 0.f};
#pragma unroll
    for (int kf = 0; kf < 4; ++kf) {
#pragma unroll
      for (int dc = 0; dc < 4; ++dc) {
        short8 af = *(const short8*)&Ks[kf * 16 + c][dc * 32 + g * 8];
        acc[kf] = __builtin_amdgcn_mfma_f32_16x16x32_bf16(af, qf[dc], acc[kf], 0, 0, 0);
      }
    }

#pragma unroll
    for (int kf = 0; kf < 4; ++kf) {
      int k0 = kt * 64 + kf * 16 + g * 4;
      const int4 mv = *(const int4*)(Mp + (size_t)qrow * S_ + k0);
      int mr[4] = {mv.x, mv.y, mv.z, mv.w};
      float4v aw;
      short4v pb;
#pragma unroll
      for (int r = 0; r < 4; ++r) {
        float x = acc[kf][r];
        x = (mr[r] == 0) ? -1e9f : x;
        float pn = __builtin_amdgcn_exp2f(x - m_run) * rl;
        aw[r] = pn;
        pb[r] = f2bf(pn);
      }
      __builtin_nontemporal_store(aw, (float4v*)(Ap + (size_t)qrow * S_ + k0));
      *(short4v*)&Psf[qrow_l][kf * 16 + g * 4] = pb;
    }

#pragma unroll
    for (int kc = 0; kc < 2; ++kc) {
      short8 pbf = *(const short8*)&Psf[qrow_l][kc * 32 + g * 8];
#pragma unroll
      for (int df = 0; df < 8; ++df) {
        short8 vf = *(const short8*)&VTs[df * 16 + c][kc * 32 + g * 8];
        acco[df] = __builtin_amdgcn_mfma_f32_16x16x32_bf16(vf, pbf, acco[df], 0, 0, 0);
      }
    }
  }

#pragma unroll
  for (int df = 0; df < 8; ++df) {
    *(float4v*)(Op + (size_t)qrow * D_ + df * 16 + g * 4) = acco[df];
  }
}

extern "C" void kernel_launch(void* const* d_in, const int* in_sizes, int n_in,
                              void* d_out, int out_size, void* d_ws, size_t ws_size,
                              hipStream_t stream) {
  const float* Q = (const float*)d_in[0];
  const float* K = (const float*)d_in[1];
  const float* V = (const float*)d_in[2];
  const int*   M = (const int*)d_in[3];
  float* Out  = (float*)d_out;
  float* Attn = Out + (size_t)B_ * H_ * S_ * D_;

  if (ws_size >= WS_NEED) {
    short* Kf = (short*)d_ws;
    short* Vf = Kf + (size_t)NSH;
    unsigned long long* Bits = (unsigned long long*)(Vf + (size_t)NSH);
    const int pgrid = NSH / 8 / 256;  // 8192
    prep_kv<<<dim3(pgrid * 2), dim3(256), 0, stream>>>(K, V, Kf, Vf, pgrid);
    prep_m<<<dim3((unsigned)(NMW / 4)), dim3(256), 0, stream>>>(M, Bits);
    sdpa_main<<<dim3(B_ * H_ * (S_ / BM)), dim3(256), 0, stream>>>(
        Q, Kf, Vf, Bits, Out, Attn);
  } else {
    sdpa_fallback<<<dim3(B_ * H_ * 32), dim3(256), 0, stream>>>(Q, K, V, M, Out, Attn);
  }
}